// Round 10
// baseline (403.975 us; speedup 1.0000x reference)
//
#include <hip/hip_runtime.h>
#include <hip/hip_bf16.h>
#include <stdint.h>

typedef __attribute__((ext_vector_type(4))) float f32x4;
typedef __attribute__((ext_vector_type(8))) short s16x8;

__device__ __forceinline__ short f2bf(float f) {
  union { float f; uint32_t u; } v; v.f = f;
  uint32_t r = v.u + 0x7FFFu + ((v.u >> 16) & 1u);
  return (short)(r >> 16);
}
__device__ __forceinline__ uint32_t pack2bf(float a, float b) {
  return (uint32_t)(uint16_t)f2bf(a) | ((uint32_t)(uint16_t)f2bf(b) << 16);
}

__device__ __forceinline__ void async16(const void* g, void* l) {
  __builtin_amdgcn_global_load_lds(
      (const __attribute__((address_space(1))) void*)g,
      (__attribute__((address_space(3))) void*)l, 16, 0, 0);
}

// -------- LDS-tiled transpose+cast: out[n][k] = bf16(in[k][n]) --------
__global__ __launch_bounds__(256) void k_transpose_cast(const float* __restrict__ in,
                                                        short* __restrict__ out,
                                                        int K, int N) {
  __shared__ float tile[64][65];
  const int bx = blockIdx.x;
  const int by = blockIdx.y;
  const int tx = threadIdx.x & 63, ty = threadIdx.x >> 6;
#pragma unroll
  for (int r = ty; r < 64; r += 4)
    tile[r][tx] = in[(size_t)(by * 64 + r) * N + bx * 64 + tx];
  __syncthreads();
#pragma unroll
  for (int r = ty; r < 64; r += 4)
    out[(size_t)(bx * 64 + r) * K + by * 64 + tx] = f2bf(tile[tx][r]);
}

// ===== persistent 256x256 8-phase bf16 GEMM (round-7 schedule) =====
// AF32=true: A is fp32, staged via regs (8 dwordx4 @ph0) -> RNE pack ->
// ds_write_b128 at ph6-tail (after vmcnt(4), which already implies A landed).
// AF32=false: original async16 A-path. B-path/barriers/epilogue identical.
#define TILE_SH 16384  // 256*64 shorts per tile

template <bool F32OUT, int NBN, bool AF32, int KK>
__global__ __launch_bounds__(512, 2) void k_gemm256p(const void* __restrict__ Av,
                                                     const short* __restrict__ Bw,
                                                     const float* __restrict__ bias,
                                                     void* __restrict__ C,
                                                     int N, int nrounds) {
  const short* A  = (const short*)Av;
  const float* Af = (const float*)Av;
  __shared__ short lds[2 * 2 * TILE_SH];  // 128 KiB
  const int t = threadIdx.x;
  const int w = t >> 6, l = t & 63;
  const int wm = w >> 2, wn = w & 3;
  const int swz = (((int)blockIdx.x & 7) << 5) + ((int)blockIdx.x >> 3);

  const int NT = KK >> 6;  // 8
  const int NS = nrounds * NT;

  auto stage = [&](const short* __restrict__ G, int row0, int kt, short* dst) {
#pragma unroll
    for (int L = 0; L < 2; ++L) {
      int cw = L * 512 + (t & ~63);
      int c = cw + l;
      int r = c >> 3, s = c & 7;
      async16(G + (size_t)(row0 + r) * KK + kt + ((s ^ (r & 7)) << 3), dst + cw * 8);
    }
  };
  auto issueA = [&](int step, int bmv, int hf) {  // AF32=false path
    int kt = step & 7;
    stage(A, bmv * 256 + hf * 128, kt * 64, lds + (kt & 1) * 32768 + hf * 8192);
  };
  auto issueB = [&](int step, int bnv, int hf) {
    int kt = step & 7;
    stage(Bw, bnv * 256 + hf * 128, kt * 64, lds + (kt & 1) * 32768 + TILE_SH + hf * 8192);
  };

  // AF32=true A-path: reg load + convert + LDS write (same swizzled content)
  float4 fa[4][2];
  auto loadA = [&](int step, int bmv) {
    int kt = step & 7;
#pragma unroll
    for (int q = 0; q < 4; ++q) {
      int hf = q >> 1;
      int cc = (q & 1) * 512 + (t & ~63) + l;
      int r = hf * 128 + (cc >> 3), sc = cc & 7;
      const float* src = Af + (size_t)(bmv * 256 + r) * KK + kt * 64 + ((sc ^ (r & 7)) << 3);
      fa[q][0] = *(const float4*)src;
      fa[q][1] = *(const float4*)(src + 4);
    }
  };
  auto writeA = [&](int step) {
    int kt = step & 7;
    short* base = lds + (kt & 1) * 32768;
#pragma unroll
    for (int q = 0; q < 4; ++q) {
      int hf = q >> 1;
      int cc = (q & 1) * 512 + (t & ~63) + l;
      int4 o;
      o.x = (int)pack2bf(fa[q][0].x, fa[q][0].y);
      o.y = (int)pack2bf(fa[q][0].z, fa[q][0].w);
      o.z = (int)pack2bf(fa[q][1].x, fa[q][1].y);
      o.w = (int)pack2bf(fa[q][1].z, fa[q][1].w);
      *(int4*)(base + hf * 8192 + (size_t)cc * 8) = o;
    }
  };

  const int g = l >> 4, v = l & 7;
  int ofsA[2], ofsB[2];
#pragma unroll
  for (int ks = 0; ks < 2; ++ks) {
    ofsA[ks] = (wm * 128 + (l & 15)) * 64 + (((ks * 4 + g) ^ v) << 3);
    ofsB[ks] = (wn * 64 + (l & 15)) * 64 + (((ks * 4 + g) ^ v) << 3);
  }

  f32x4 acc[8][4] = {};
  s16x8 bfr[4][2];

  // prologue
  {
    const int bm0 = swz / NBN, bn0 = swz % NBN;
    if (AF32) {
      loadA(0, bm0);
      issueB(0, bn0, 0); issueB(0, bn0, 1);
      issueB(1, bn0, 0); issueB(1, bn0, 1);
      asm volatile("s_waitcnt vmcnt(4)" ::: "memory");  // A0 + B0 landed
      writeA(0);
      asm volatile("s_waitcnt lgkmcnt(0)" ::: "memory");
    } else {
      issueB(0, bn0, 0); issueB(0, bn0, 1);
      issueA(0, bm0, 0); issueA(0, bm0, 1);
      issueB(1, bn0, 0); issueB(1, bn0, 1);
      asm volatile("s_waitcnt vmcnt(4)" ::: "memory");
    }
  }
  __builtin_amdgcn_s_barrier();

  auto tailStd = [&](int s1v, int s2v) {  // AF32=false
    if (s2v < NS) { asm volatile("s_waitcnt vmcnt(4)" ::: "memory"); }
    else if (s1v < NS) { asm volatile("s_waitcnt vmcnt(0)" ::: "memory"); }
  };
  auto tailF32 = [&](int s1v, int s2v) {  // AF32=true
    if (s2v < NS) { asm volatile("s_waitcnt vmcnt(4)" ::: "memory"); }
    else if (s1v < NS) { asm volatile("s_waitcnt vmcnt(0)" ::: "memory"); }
    if (s1v < NS) {
      writeA(s1v);
      asm volatile("s_waitcnt lgkmcnt(0)" ::: "memory");
    }
  };

#define PHASE(AI0, STAGE_STMT, TAIL_STMT)                                                                      \
  {                                                                                                            \
    s16x8 a00 = *(const s16x8*)(Ab + ofsA[0] + (AI0) * 1024);                                                  \
    s16x8 a01 = *(const s16x8*)(Ab + ofsA[1] + (AI0) * 1024);                                                  \
    s16x8 a10 = *(const s16x8*)(Ab + ofsA[0] + ((AI0) + 1) * 1024);                                            \
    s16x8 a11 = *(const s16x8*)(Ab + ofsA[1] + ((AI0) + 1) * 1024);                                            \
    STAGE_STMT;                                                                                                \
    __builtin_amdgcn_s_barrier();                                                                              \
    asm volatile("s_waitcnt lgkmcnt(0)" ::: "memory");                                                         \
    __builtin_amdgcn_s_setprio(1);                                                                             \
    _Pragma("unroll")                                                                                          \
    for (int nj = 0; nj < 4; ++nj) {                                                                           \
      acc[(AI0)][nj] = __builtin_amdgcn_mfma_f32_16x16x32_bf16(a00, bfr[nj][0], acc[(AI0)][nj], 0, 0, 0);      \
      acc[(AI0)][nj] = __builtin_amdgcn_mfma_f32_16x16x32_bf16(a01, bfr[nj][1], acc[(AI0)][nj], 0, 0, 0);      \
      acc[(AI0) + 1][nj] = __builtin_amdgcn_mfma_f32_16x16x32_bf16(a10, bfr[nj][0], acc[(AI0) + 1][nj], 0, 0, 0); \
      acc[(AI0) + 1][nj] = __builtin_amdgcn_mfma_f32_16x16x32_bf16(a11, bfr[nj][1], acc[(AI0) + 1][nj], 0, 0, 0); \
    }                                                                                                          \
    __builtin_amdgcn_s_setprio(0);                                                                             \
    TAIL_STMT;                                                                                                 \
    __builtin_amdgcn_s_barrier();                                                                              \
  }

  for (int j = 0; j < nrounds; ++j) {
    const int tauc = swz + (j << 8);
    const int bmc = tauc / NBN, bnc = tauc % NBN;
    for (int T = 0; T < NT; ++T) {
      const int s = (j << 3) + T;
      const int s1 = s + 1, s2 = s + 2;
      const int tau1 = swz + (((s1) >> 3) << 8);
      const int tau2 = swz + (((s2) >> 3) << 8);
      const int bm1 = tau1 / NBN;
      const int bn2 = tau2 % NBN;
      const short* Ab = lds + (T & 1) * 32768;
      const short* Bb = Ab + TILE_SH;
#pragma unroll
      for (int nj = 0; nj < 4; ++nj)
#pragma unroll
        for (int ks = 0; ks < 2; ++ks)
          bfr[nj][ks] = *(const s16x8*)(Bb + ofsB[ks] + nj * 1024);

      if (AF32) {
        PHASE(0, if (s1 < NS) loadA(s1, bm1), );
        PHASE(2, , );
        PHASE(4, if (s2 < NS) issueB(s2, bn2, 0), );
        PHASE(6, if (s2 < NS) issueB(s2, bn2, 1), tailF32(s1, s2));
      } else {
        PHASE(0, if (s1 < NS) issueA(s1, bm1, 0), );
        PHASE(2, if (s1 < NS) issueA(s1, bm1, 1), );
        PHASE(4, if (s2 < NS) issueB(s2, bn2, 0), );
        PHASE(6, if (s2 < NS) issueB(s2, bn2, 1), tailStd(s1, s2));
      }
    }

    // epilogue tile j: stores overlap next tile's K-loop
#pragma unroll
    for (int ai = 0; ai < 8; ++ai)
#pragma unroll
      for (int nj = 0; nj < 4; ++nj) {
        int col = bnc * 256 + wn * 64 + nj * 16 + (l & 15);
        float bv = bias[col];
#pragma unroll
        for (int r = 0; r < 4; ++r) {
          int row = bmc * 256 + wm * 128 + ai * 16 + (l >> 4) * 4 + r;
          float vv = acc[ai][nj][r] + bv;
          if (F32OUT)
            ((float*)C)[(size_t)row * N + col] = vv;
          else
            ((short*)C)[(size_t)row * N + col] = f2bf(vv);
        }
      }
#pragma unroll
    for (int ai = 0; ai < 8; ++ai)
#pragma unroll
      for (int nj = 0; nj < 4; ++nj)
        acc[ai][nj] = (f32x4){0.f, 0.f, 0.f, 0.f};
  }
#undef PHASE
}

// ============== fused window attention v2: swapped QK^T, 1 wave/(b,h) ==============
__global__ __launch_bounds__(256) void k_attn(const short* __restrict__ qkv,
                                              const float* __restrict__ mask,
                                              const float* __restrict__ bias_table,
                                              short* __restrict__ Y) {
  __shared__ float mask_lds[64 * 64];   // [n][m ^ ((n&7)<<2)]
  __shared__ float bias_lds[4][128];
  __shared__ short p_lds[4][64][72];
  __shared__ short v_lds[4][64][40];

  const int t = threadIdx.x, wv = t >> 6, ln = t & 63;
  const int b = blockIdx.x;
  const int h = blockIdx.y * 4 + wv;
  const int hi = ln >> 4, lo = ln & 15;

  const float4* mk = (const float4*)(mask + (size_t)(b & 63) * 4096);
#pragma unroll
  for (int u = 0; u < 4; ++u) {
    int idx = t + 256 * u;
    int row = idx >> 4, c4 = (idx & 15) * 4;
    *(float4*)&mask_lds[row * 64 + (c4 ^ ((row & 7) << 2))] = mk[idx];
  }
  for (int u = ln; u < 127; u += 64) bias_lds[wv][u] = bias_table[u * 16 + h];

  const short* qb = qkv + (size_t)b * 64 * 1536 + h * 32;
  const short* vg = qb + 1024;
#pragma unroll
  for (int u = 0; u < 4; ++u) {
    int row = u * 16 + (ln >> 2), c8 = (ln & 3) * 8;
    *(s16x8*)&v_lds[wv][row][c8] = *(const s16x8*)(vg + (size_t)row * 1536 + c8);
  }
  __syncthreads();

  s16x8 qf[4], kf[4];
#pragma unroll
  for (int i = 0; i < 4; ++i) {
    qf[i] = *(const s16x8*)(qb + (size_t)(16 * i + lo) * 1536 + hi * 8);
    kf[i] = *(const s16x8*)(qb + (size_t)(16 * i + lo) * 1536 + 512 + hi * 8);
  }
  f32x4 s2[4][4] = {};
#pragma unroll
  for (int j = 0; j < 4; ++j)
#pragma unroll
    for (int i = 0; i < 4; ++i)
      s2[j][i] = __builtin_amdgcn_mfma_f32_16x16x32_bf16(kf[j], qf[i], s2[j][i], 0, 0, 0);

  const float scale = 0.17677669529663687f;
#pragma unroll
  for (int i = 0; i < 4; ++i) {
    const int n = 16 * i + lo;
    const int msw = (n & 7) << 2;
    float x[16];
    float vmax = -1e30f;
#pragma unroll
    for (int j = 0; j < 4; ++j)
#pragma unroll
      for (int r = 0; r < 4; ++r) {
        int m = 16 * j + 4 * hi + r;
        float xx = s2[j][i][r] * scale + bias_lds[wv][n - m + 63] +
                   mask_lds[n * 64 + (m ^ msw)];
        x[j * 4 + r] = xx;
        vmax = fmaxf(vmax, xx);
      }
    vmax = fmaxf(vmax, __shfl_xor(vmax, 16, 64));
    vmax = fmaxf(vmax, __shfl_xor(vmax, 32, 64));
    float sum = 0.f;
#pragma unroll
    for (int u = 0; u < 16; ++u) {
      x[u] = __expf(x[u] - vmax);
      sum += x[u];
    }
    sum += __shfl_xor(sum, 16, 64);
    sum += __shfl_xor(sum, 32, 64);
    float rsv = 1.0f / sum;
#pragma unroll
    for (int j = 0; j < 4; ++j)
#pragma unroll
      for (int rp = 0; rp < 2; ++rp)
        *(uint32_t*)&p_lds[wv][n][16 * j + 4 * hi + rp * 2] =
            pack2bf(x[j * 4 + rp * 2] * rsv, x[j * 4 + rp * 2 + 1] * rsv);
  }

  f32x4 o2[2][4] = {};
#pragma unroll
  for (int kk = 0; kk < 2; ++kk) {
    s16x8 pa[4];
#pragma unroll
    for (int i2 = 0; i2 < 4; ++i2)
      pa[i2] = *(const s16x8*)&p_lds[wv][16 * i2 + lo][kk * 32 + hi * 8];
#pragma unroll
    for (int j2 = 0; j2 < 2; ++j2) {
      s16x8 vf;
#pragma unroll
      for (int jj = 0; jj < 8; ++jj)
        vf[jj] = v_lds[wv][kk * 32 + hi * 8 + jj][16 * j2 + lo];
#pragma unroll
      for (int i2 = 0; i2 < 4; ++i2)
        o2[j2][i2] = __builtin_amdgcn_mfma_f32_16x16x32_bf16(vf, pa[i2], o2[j2][i2], 0, 0, 0);
    }
  }

  const int rr = h * 64 + (b >> 4);
#pragma unroll
  for (int i2 = 0; i2 < 4; ++i2) {
    int ss = (b & 15) * 4 + i2;
    short* yr = Y + ((size_t)rr * 64 + ss) * 512 + lo * 32 + 4 * hi;
#pragma unroll
    for (int j2 = 0; j2 < 2; ++j2) {
      uint2 pk;
      pk.x = pack2bf(o2[j2][i2][0], o2[j2][i2][1]);
      pk.y = pack2bf(o2[j2][i2][2], o2[j2][i2][3]);
      *(uint2*)(yr + 16 * j2) = pk;
    }
  }
}

extern "C" void kernel_launch(void* const* d_in, const int* in_sizes, int n_in,
                              void* d_out, int out_size, void* d_ws, size_t ws_size,
                              hipStream_t stream) {
  const float* x      = (const float*)d_in[0];
  const float* mask   = (const float*)d_in[1];
  const float* qkv_w  = (const float*)d_in[2];
  const float* qkv_b  = (const float*)d_in[3];
  const float* proj_w = (const float*)d_in[4];
  const float* proj_b = (const float*)d_in[5];
  const float* btab   = (const float*)d_in[6];
  float* out = (float*)d_out;

  char* w = (char*)d_ws;
  short* qkv_ws = (short*)w;                                             // 192 MiB
  short* Y      = (short*)(w + (size_t)65536 * 1536 * 2);                // 64 MiB
  short* wT     = (short*)(w + (size_t)65536 * 1536 * 2 + (size_t)65536 * 512 * 2);
  short* projT  = wT + 1536 * 512;

  k_transpose_cast<<<dim3(24, 8), 256, 0, stream>>>(qkv_w, wT, 512, 1536);
  k_transpose_cast<<<dim3(8, 8), 256, 0, stream>>>(proj_w, projT, 512, 512);
  k_gemm256p<false, 6, true, 512><<<256, 512, 0, stream>>>(x, wT, qkv_b, qkv_ws, 1536, 6);
  k_attn<<<dim3(1024, 4), 256, 0, stream>>>(qkv_ws, mask, btab, Y);
  k_gemm256p<true, 2, false, 512><<<256, 512, 0, stream>>>(Y, projT, proj_b, out, 512, 2);
}

// Round 11
// 289.414 us; speedup vs baseline: 1.3958x; 1.3958x over previous
//
#include <hip/hip_runtime.h>
#include <hip/hip_bf16.h>
#include <stdint.h>

typedef __attribute__((ext_vector_type(4))) float f32x4;
typedef __attribute__((ext_vector_type(8))) short s16x8;

__device__ __forceinline__ short f2bf(float f) {
  union { float f; uint32_t u; } v; v.f = f;
  uint32_t r = v.u + 0x7FFFu + ((v.u >> 16) & 1u);
  return (short)(r >> 16);
}
__device__ __forceinline__ uint32_t pack2bf(float a, float b) {
  return (uint32_t)(uint16_t)f2bf(a) | ((uint32_t)(uint16_t)f2bf(b) << 16);
}

__device__ __forceinline__ void async16(const void* g, void* l) {
  __builtin_amdgcn_global_load_lds(
      (const __attribute__((address_space(1))) void*)g,
      (__attribute__((address_space(3))) void*)l, 16, 0, 0);
}

// ---------------- cast x (fp32 -> bf16), 8 elems/thread ----------------
__global__ __launch_bounds__(256) void k_cast_bf16(const float* __restrict__ in,
                                                   short* __restrict__ out, int n8) {
  int i = blockIdx.x * 256 + threadIdx.x;
  if (i >= n8) return;
  const float4* p = (const float4*)in + (size_t)i * 2;
  float4 a = p[0], b = p[1];
  s16x8 o;
  o[0] = f2bf(a.x); o[1] = f2bf(a.y); o[2] = f2bf(a.z); o[3] = f2bf(a.w);
  o[4] = f2bf(b.x); o[5] = f2bf(b.y); o[6] = f2bf(b.z); o[7] = f2bf(b.w);
  ((s16x8*)out)[i] = o;
}

// -------- LDS-tiled transpose+cast: out[n][k] = bf16(in[k][n]) --------
__global__ __launch_bounds__(256) void k_transpose_cast(const float* __restrict__ in,
                                                        short* __restrict__ out,
                                                        int K, int N) {
  __shared__ float tile[64][65];
  const int bx = blockIdx.x;
  const int by = blockIdx.y;
  const int tx = threadIdx.x & 63, ty = threadIdx.x >> 6;
#pragma unroll
  for (int r = ty; r < 64; r += 4)
    tile[r][tx] = in[(size_t)(by * 64 + r) * N + bx * 64 + tx];
  __syncthreads();
#pragma unroll
  for (int r = ty; r < 64; r += 4)
    out[(size_t)(bx * 64 + r) * K + by * 64 + tx] = f2bf(tile[tx][r]);
}

// ===== persistent 256x256 8-phase bf16 GEMM (round-7/9 proven schedule) =====
// OUTMODE: 0 = bf16 C[row*N+col], 1 = f32 C[row*N+col],
//          2 = bf16 qkv2[b][h][sel][n][d]  (attention-native; address-only change)
#define TILE_SH 16384  // 256*64 shorts per tile

template <int OUTMODE, int NBN, int KK>
__global__ __launch_bounds__(512, 2) void k_gemm256p(const short* __restrict__ A,
                                                     const short* __restrict__ Bw,
                                                     const float* __restrict__ bias,
                                                     void* __restrict__ C,
                                                     int N, int nrounds) {
  __shared__ short lds[2 * 2 * TILE_SH];  // 128 KiB
  const int t = threadIdx.x;
  const int w = t >> 6, l = t & 63;
  const int wm = w >> 2, wn = w & 3;
  const int swz = (((int)blockIdx.x & 7) << 5) + ((int)blockIdx.x >> 3);

  const int NT = KK >> 6;  // 8
  const int NS = nrounds * NT;

  auto stage = [&](const short* __restrict__ G, int row0, int kt, short* dst) {
#pragma unroll
    for (int L = 0; L < 2; ++L) {
      int cw = L * 512 + (t & ~63);
      int c = cw + l;
      int r = c >> 3, s = c & 7;
      async16(G + (size_t)(row0 + r) * KK + kt + ((s ^ (r & 7)) << 3), dst + cw * 8);
    }
  };
  auto issueA = [&](int step, int bmv, int hf) {
    int kt = step & 7;
    stage(A, bmv * 256 + hf * 128, kt * 64, lds + (kt & 1) * 32768 + hf * 8192);
  };
  auto issueB = [&](int step, int bnv, int hf) {
    int kt = step & 7;
    stage(Bw, bnv * 256 + hf * 128, kt * 64, lds + (kt & 1) * 32768 + TILE_SH + hf * 8192);
  };

  const int g = l >> 4, v = l & 7;
  int ofsA[2], ofsB[2];
#pragma unroll
  for (int ks = 0; ks < 2; ++ks) {
    ofsA[ks] = (wm * 128 + (l & 15)) * 64 + (((ks * 4 + g) ^ v) << 3);
    ofsB[ks] = (wn * 64 + (l & 15)) * 64 + (((ks * 4 + g) ^ v) << 3);
  }

  f32x4 acc[8][4] = {};
  s16x8 bfr[4][2];

  {
    const int bm0 = swz / NBN, bn0 = swz % NBN;
    issueB(0, bn0, 0); issueB(0, bn0, 1);
    issueA(0, bm0, 0); issueA(0, bm0, 1);
    issueB(1, bn0, 0); issueB(1, bn0, 1);
  }
  asm volatile("s_waitcnt vmcnt(4)" ::: "memory");
  __builtin_amdgcn_s_barrier();

#define PHASE(AI0, STAGE_STMT, TAIL_STMT)                                                                      \
  {                                                                                                            \
    s16x8 a00 = *(const s16x8*)(Ab + ofsA[0] + (AI0) * 1024);                                                  \
    s16x8 a01 = *(const s16x8*)(Ab + ofsA[1] + (AI0) * 1024);                                                  \
    s16x8 a10 = *(const s16x8*)(Ab + ofsA[0] + ((AI0) + 1) * 1024);                                            \
    s16x8 a11 = *(const s16x8*)(Ab + ofsA[1] + ((AI0) + 1) * 1024);                                            \
    STAGE_STMT;                                                                                                \
    __builtin_amdgcn_s_barrier();                                                                              \
    asm volatile("s_waitcnt lgkmcnt(0)" ::: "memory");                                                         \
    __builtin_amdgcn_s_setprio(1);                                                                             \
    _Pragma("unroll")                                                                                          \
    for (int nj = 0; nj < 4; ++nj) {                                                                           \
      acc[(AI0)][nj] = __builtin_amdgcn_mfma_f32_16x16x32_bf16(a00, bfr[nj][0], acc[(AI0)][nj], 0, 0, 0);      \
      acc[(AI0)][nj] = __builtin_amdgcn_mfma_f32_16x16x32_bf16(a01, bfr[nj][1], acc[(AI0)][nj], 0, 0, 0);      \
      acc[(AI0) + 1][nj] = __builtin_amdgcn_mfma_f32_16x16x32_bf16(a10, bfr[nj][0], acc[(AI0) + 1][nj], 0, 0, 0); \
      acc[(AI0) + 1][nj] = __builtin_amdgcn_mfma_f32_16x16x32_bf16(a11, bfr[nj][1], acc[(AI0) + 1][nj], 0, 0, 0); \
    }                                                                                                          \
    __builtin_amdgcn_s_setprio(0);                                                                             \
    TAIL_STMT;                                                                                                 \
    __builtin_amdgcn_s_barrier();                                                                              \
  }

  for (int j = 0; j < nrounds; ++j) {
    const int tauc = swz + (j << 8);
    const int bmc = tauc / NBN, bnc = tauc % NBN;
    for (int T = 0; T < NT; ++T) {
      const int s = (j << 3) + T;
      const int s1 = s + 1, s2 = s + 2;
      const int tau1 = swz + (((s1) >> 3) << 8);
      const int tau2 = swz + (((s2) >> 3) << 8);
      const int bm1 = tau1 / NBN;
      const int bn2 = tau2 % NBN;
      const short* Ab = lds + (T & 1) * 32768;
      const short* Bb = Ab + TILE_SH;
#pragma unroll
      for (int nj = 0; nj < 4; ++nj)
#pragma unroll
        for (int ks = 0; ks < 2; ++ks)
          bfr[nj][ks] = *(const s16x8*)(Bb + ofsB[ks] + nj * 1024);

      PHASE(0, if (s1 < NS) issueA(s1, bm1, 0), );
      PHASE(2, if (s1 < NS) issueA(s1, bm1, 1), );
      PHASE(4, if (s2 < NS) issueB(s2, bn2, 0), );
      PHASE(6, if (s2 < NS) issueB(s2, bn2, 1),
            if (s2 < NS) { asm volatile("s_waitcnt vmcnt(4)" ::: "memory"); }
            else if (s1 < NS) { asm volatile("s_waitcnt vmcnt(0)" ::: "memory"); });
    }

    // epilogue tile j: stores overlap next tile's K-loop
#pragma unroll
    for (int ai = 0; ai < 8; ++ai)
#pragma unroll
      for (int nj = 0; nj < 4; ++nj) {
        int col = bnc * 256 + wn * 64 + nj * 16 + (l & 15);
        float bv = bias[col];
#pragma unroll
        for (int r = 0; r < 4; ++r) {
          int row = bmc * 256 + wm * 128 + ai * 16 + (l >> 4) * 4 + r;
          float vv = acc[ai][nj][r] + bv;
          if (OUTMODE == 1) {
            ((float*)C)[(size_t)row * N + col] = vv;
          } else if (OUTMODE == 0) {
            ((short*)C)[(size_t)row * N + col] = f2bf(vv);
          } else {
            // qkv2[b][h][sel][n][d]: b=row>>6, n=row&63, sel=col>>9, h=(col>>5)&15, d=col&31
            int bb = row >> 6, nn = row & 63;
            int sel = col >> 9, hh = (col >> 5) & 15, dd = col & 31;
            ((short*)C)[(((size_t)(bb * 48 + hh * 3 + sel)) << 11) + (nn << 5) + dd] = f2bf(vv);
          }
        }
      }
#pragma unroll
    for (int ai = 0; ai < 8; ++ai)
#pragma unroll
      for (int nj = 0; nj < 4; ++nj)
        acc[ai][nj] = (f32x4){0.f, 0.f, 0.f, 0.f};
  }
#undef PHASE
}

// ============== fused window attention v3: qkv2 layout, swapped QK^T ==============
// qkv2[b][h][sel][n][d]: per (b,h) q,k,v each contiguous 4 KB -> b128 frag loads.
__global__ __launch_bounds__(256) void k_attn(const short* __restrict__ qkv2,
                                              const float* __restrict__ mask,
                                              const float* __restrict__ bias_table,
                                              short* __restrict__ Y) {
  __shared__ float mask_lds[64 * 64];   // [n][m ^ ((n&7)<<2)]
  __shared__ float bias_lds[4][128];
  __shared__ short p_lds[4][64][72];
  __shared__ short v_lds[4][64][40];

  const int t = threadIdx.x, wv = t >> 6, ln = t & 63;
  const int b = blockIdx.x;
  const int h = blockIdx.y * 4 + wv;
  const int hi = ln >> 4, lo = ln & 15;

  const float4* mk = (const float4*)(mask + (size_t)(b & 63) * 4096);
#pragma unroll
  for (int u = 0; u < 4; ++u) {
    int idx = t + 256 * u;
    int row = idx >> 4, c4 = (idx & 15) * 4;
    *(float4*)&mask_lds[row * 64 + (c4 ^ ((row & 7) << 2))] = mk[idx];
  }
  for (int u = ln; u < 127; u += 64) bias_lds[wv][u] = bias_table[u * 16 + h];

  const short* base = qkv2 + ((size_t)(b * 16 + h)) * 3 * 2048;
  const short* vg = base + 4096;
#pragma unroll
  for (int u = 0; u < 4; ++u) {
    int row = u * 16 + (ln >> 2), c8 = (ln & 3) * 8;
    *(s16x8*)&v_lds[wv][row][c8] = *(const s16x8*)(vg + row * 32 + c8);
  }
  __syncthreads();

  s16x8 qf[4], kf[4];
#pragma unroll
  for (int i = 0; i < 4; ++i) {
    qf[i] = *(const s16x8*)(base + (16 * i + lo) * 32 + hi * 8);
    kf[i] = *(const s16x8*)(base + 2048 + (16 * i + lo) * 32 + hi * 8);
  }
  f32x4 s2[4][4] = {};
#pragma unroll
  for (int j = 0; j < 4; ++j)
#pragma unroll
    for (int i = 0; i < 4; ++i)
      s2[j][i] = __builtin_amdgcn_mfma_f32_16x16x32_bf16(kf[j], qf[i], s2[j][i], 0, 0, 0);

  const float scale = 0.17677669529663687f;
#pragma unroll
  for (int i = 0; i < 4; ++i) {
    const int n = 16 * i + lo;
    const int msw = (n & 7) << 2;
    float x[16];
    float vmax = -1e30f;
#pragma unroll
    for (int j = 0; j < 4; ++j)
#pragma unroll
      for (int r = 0; r < 4; ++r) {
        int m = 16 * j + 4 * hi + r;
        float xx = s2[j][i][r] * scale + bias_lds[wv][n - m + 63] +
                   mask_lds[n * 64 + (m ^ msw)];
        x[j * 4 + r] = xx;
        vmax = fmaxf(vmax, xx);
      }
    vmax = fmaxf(vmax, __shfl_xor(vmax, 16, 64));
    vmax = fmaxf(vmax, __shfl_xor(vmax, 32, 64));
    float sum = 0.f;
#pragma unroll
    for (int u = 0; u < 16; ++u) {
      x[u] = __expf(x[u] - vmax);
      sum += x[u];
    }
    sum += __shfl_xor(sum, 16, 64);
    sum += __shfl_xor(sum, 32, 64);
    float rsv = 1.0f / sum;
#pragma unroll
    for (int j = 0; j < 4; ++j)
#pragma unroll
      for (int rp = 0; rp < 2; ++rp)
        *(uint32_t*)&p_lds[wv][n][16 * j + 4 * hi + rp * 2] =
            pack2bf(x[j * 4 + rp * 2] * rsv, x[j * 4 + rp * 2 + 1] * rsv);
  }

  f32x4 o2[2][4] = {};
#pragma unroll
  for (int kk = 0; kk < 2; ++kk) {
    s16x8 pa[4];
#pragma unroll
    for (int i2 = 0; i2 < 4; ++i2)
      pa[i2] = *(const s16x8*)&p_lds[wv][16 * i2 + lo][kk * 32 + hi * 8];
#pragma unroll
    for (int j2 = 0; j2 < 2; ++j2) {
      s16x8 vf;
#pragma unroll
      for (int jj = 0; jj < 8; ++jj)
        vf[jj] = v_lds[wv][kk * 32 + hi * 8 + jj][16 * j2 + lo];
#pragma unroll
      for (int i2 = 0; i2 < 4; ++i2)
        o2[j2][i2] = __builtin_amdgcn_mfma_f32_16x16x32_bf16(vf, pa[i2], o2[j2][i2], 0, 0, 0);
    }
  }

  const int rr = h * 64 + (b >> 4);
#pragma unroll
  for (int i2 = 0; i2 < 4; ++i2) {
    int ss = (b & 15) * 4 + i2;
    short* yr = Y + ((size_t)rr * 64 + ss) * 512 + lo * 32 + 4 * hi;
#pragma unroll
    for (int j2 = 0; j2 < 2; ++j2) {
      uint2 pk;
      pk.x = pack2bf(o2[j2][i2][0], o2[j2][i2][1]);
      pk.y = pack2bf(o2[j2][i2][2], o2[j2][i2][3]);
      *(uint2*)(yr + 16 * j2) = pk;
    }
  }
}

extern "C" void kernel_launch(void* const* d_in, const int* in_sizes, int n_in,
                              void* d_out, int out_size, void* d_ws, size_t ws_size,
                              hipStream_t stream) {
  const float* x      = (const float*)d_in[0];
  const float* mask   = (const float*)d_in[1];
  const float* qkv_w  = (const float*)d_in[2];
  const float* qkv_b  = (const float*)d_in[3];
  const float* proj_w = (const float*)d_in[4];
  const float* proj_b = (const float*)d_in[5];
  const float* btab   = (const float*)d_in[6];
  float* out = (float*)d_out;

  char* w = (char*)d_ws;
  short* qkv_ws = (short*)w;                                             // 192 MiB
  short* xbf    = (short*)(w + (size_t)65536 * 1536 * 2);                // 64 MiB
  short* Y      = xbf;                                                   // reuse after GEMM1
  short* wT     = (short*)(w + (size_t)65536 * 1536 * 2 + (size_t)65536 * 512 * 2);
  short* projT  = wT + 1536 * 512;

  k_cast_bf16<<<16384, 256, 0, stream>>>(x, xbf, 33554432 / 8);
  k_transpose_cast<<<dim3(24, 8), 256, 0, stream>>>(qkv_w, wT, 512, 1536);
  k_transpose_cast<<<dim3(8, 8), 256, 0, stream>>>(proj_w, projT, 512, 512);
  k_gemm256p<2, 6, 512><<<256, 512, 0, stream>>>(xbf, wT, qkv_b, qkv_ws, 1536, 6);
  k_attn<<<dim3(1024, 4), 256, 0, stream>>>(qkv_ws, mask, btab, Y);
  k_gemm256p<1, 2, 512><<<256, 512, 0, stream>>>(Y, projT, proj_b, out, 512, 2);
}